// Round 2
// baseline (470.096 us; speedup 1.0000x reference)
//
#include <hip/hip_runtime.h>

#define NN 50000
#define NP 50176        // padded per-copy stride (multiple of 256)
#define TT 518
#define KC 32
#define LL 163
#define HH 128
#define EE 1600000
#define NB 196          // node blocks: 196*256 = 50176 >= NN
#define NCOPY 8

// deg copies: deg8[(tid&7)*NP + col] += ea   (8 copies cut atomic contention 8x)
__global__ __launch_bounds__(256) void k_deg(const int* __restrict__ col,
                                             const float* __restrict__ ea,
                                             float* __restrict__ deg8) {
  int e = blockIdx.x * 256 + threadIdx.x;
  if (e < EE) atomicAdd(&deg8[(threadIdx.x & 7) * NP + col[e]], ea[e]);
}

// dinv = rsqrt(1 + sum of 8 deg copies)
__global__ __launch_bounds__(256) void k_dinv(const float* __restrict__ deg8,
                                              float* __restrict__ dinv) {
  int i = blockIdx.x * 256 + threadIdx.x;
  if (i < NN) {
    float s = 1.0f;
#pragma unroll
    for (int j = 0; j < NCOPY; ++j) s += deg8[j * NP + i];
    dinv[i] = rsqrtf(s);
  }
}

// coef copies: coef8[copy][row] += dinv[row]*ea*dinv[col]
__global__ __launch_bounds__(256) void k_coef(const int* __restrict__ row,
                                              const int* __restrict__ col,
                                              const float* __restrict__ ea,
                                              const float* __restrict__ dinv,
                                              float* __restrict__ coef8) {
  int e = blockIdx.x * 256 + threadIdx.x;
  if (e < EE) {
    int r = row[e];
    atomicAdd(&coef8[(threadIdx.x & 7) * NP + r],
              dinv[r] * ea[e] * dinv[col[e]]);
  }
}

// c[i] = dinv[i]^2 + sum of 8 coef copies
__global__ __launch_bounds__(256) void k_csum(const float* __restrict__ coef8,
                                              const float* __restrict__ dinv,
                                              float* __restrict__ c) {
  int i = blockIdx.x * 256 + threadIdx.x;
  if (i < NN) {
    float di = dinv[i];
    float s = di * di;
#pragma unroll
    for (int j = 0; j < NCOPY; ++j) s += coef8[j * NP + i];
    c[i] = s;
  }
}

// v[l] += sum_n c[n] * relu(conv1d(x[:,n], w[n]) + b[n])[l]
// One thread per node column; 64-slot register ring, prefetch ~11 iters ahead.
// PH = (96*lc) & 63 = (lc&1)*32, a compile-time template arg so all ring
// indices are constants (no VGPR-indexed scratch).
template <int PH>
__device__ __forceinline__ void conv_body(const float* __restrict__ xp,
                                          const float* __restrict__ w,
                                          float bn, float cn, int base_t,
                                          int l0, float* vloc, int lane) {
  float ring[64];
  // initial fill: t = base_t + j, j = 0..63 (clamped loads land in slots that
  // are never read by a valid dot before being overwritten)
#pragma unroll
  for (int j = 0; j < 64; ++j) {
    int t = base_t + j;
    int tc = t < TT ? t : TT - 1;
    ring[(PH + j) & 63] = xp[(size_t)tc * NN];
  }
#pragma unroll
  for (int u = 0; u < 32; ++u) {
    if (l0 + u >= LL) break;  // uniform per block (lc==5 tail)
    float h0 = 0.f, h1 = 0.f, h2 = 0.f, h3 = 0.f;
#pragma unroll
    for (int k = 0; k < KC; k += 4) {
      h0 += ring[(PH + 3 * u + k    ) & 63] * w[k];
      h1 += ring[(PH + 3 * u + k + 1) & 63] * w[k + 1];
      h2 += ring[(PH + 3 * u + k + 2) & 63] * w[k + 2];
      h3 += ring[(PH + 3 * u + k + 3) & 63] * w[k + 3];
    }
    float hv = (h0 + h1) + (h2 + h3) + bn;
    hv = hv > 0.f ? hv : 0.f;
    float val = cn * hv;
#pragma unroll
    for (int off = 1; off < 64; off <<= 1) val += __shfl_xor(val, off, 64);
    if (lane == 0) atomicAdd(&vloc[u], val);
    // prefetch t = base_t + 3u + 64..66 into the 3 slots consumed this iter
#pragma unroll
    for (int j = 0; j < 3; ++j) {
      int t = base_t + 3 * u + 64 + j;
      int tc = t < TT ? t : TT - 1;
      ring[(PH + 3 * u + j) & 63] = xp[(size_t)tc * NN];
    }
  }
}

__global__ __launch_bounds__(256) void k_conv(const float* __restrict__ x,
                                              const float* __restrict__ cw,
                                              const float* __restrict__ cb,
                                              const float* __restrict__ c,
                                              float* __restrict__ v) {
  __shared__ float vloc[32];
  int tid = threadIdx.x;
  if (tid < 32) vloc[tid] = 0.f;
  __syncthreads();

  int nb = blockIdx.x % NB;
  int lc = blockIdx.x / NB;      // 0..5
  int n = nb * 256 + tid;
  int nc = n < NN ? n : NN - 1;  // clamp for safe loads; cn=0 kills contribution
  float cn = n < NN ? c[n] : 0.f;
  float bn = cb[nc];

  float w[KC];
#pragma unroll
  for (int k = 0; k < KC; ++k) w[k] = cw[nc * KC + k];

  const float* xp = x + nc;
  int base_t = 96 * lc;
  int l0 = 32 * lc;
  int lane = tid & 63;

  if (lc & 1) conv_body<32>(xp, w, bn, cn, base_t, l0, vloc, lane);
  else        conv_body<0>(xp, w, bn, cn, base_t, l0, vloc, lane);

  __syncthreads();
  if (tid < 32 && l0 + tid < LL) atomicAdd(&v[l0 + tid], vloc[tid]);
}

// out[h] = (sum_l v[l]*W[l][h]) / N + gcn_b[h]
__global__ __launch_bounds__(128) void k_out(const float* __restrict__ v,
                                             const float* __restrict__ W,
                                             const float* __restrict__ b,
                                             float* __restrict__ out) {
  int h = threadIdx.x;
  float s = 0.f;
  for (int l = 0; l < LL; ++l) s += v[l] * W[l * HH + h];
  out[h] = s * (1.0f / NN) + b[h];
}

extern "C" void kernel_launch(void* const* d_in, const int* in_sizes, int n_in,
                              void* d_out, int out_size, void* d_ws, size_t ws_size,
                              hipStream_t stream) {
  const float* x  = (const float*)d_in[0];
  const int*   ei = (const int*)d_in[1];
  const float* ea = (const float*)d_in[2];
  const float* cw = (const float*)d_in[3];
  const float* cb = (const float*)d_in[4];
  const float* gW = (const float*)d_in[5];
  const float* gb = (const float*)d_in[6];
  float* out = (float*)d_out;

  float* ws    = (float*)d_ws;
  float* deg8  = ws;                         // NCOPY*NP floats
  float* coef8 = ws + NCOPY * NP;            // NCOPY*NP floats
  float* v     = ws + 2 * NCOPY * NP;        // 256 floats (163 used)
  float* dinv  = ws + 2 * NCOPY * NP + 256;  // NP floats
  float* c     = ws + 2 * NCOPY * NP + 256 + NP;

  const int* row = ei;
  const int* col = ei + EE;

  // zero deg8 + coef8 + v in one contiguous memset
  hipMemsetAsync(deg8, 0, (2 * NCOPY * NP + 256) * sizeof(float), stream);

  k_deg <<<(EE + 255) / 256, 256, 0, stream>>>(col, ea, deg8);
  k_dinv<<<(NN + 255) / 256, 256, 0, stream>>>(deg8, dinv);
  k_coef<<<(EE + 255) / 256, 256, 0, stream>>>(row, col, ea, dinv, coef8);
  k_csum<<<(NN + 255) / 256, 256, 0, stream>>>(coef8, dinv, c);
  k_conv<<<NB * 6, 256, 0, stream>>>(x, cw, cb, c, v);
  k_out <<<1, 128, 0, stream>>>(v, gW, gb, out);
}

// Round 3
// 408.101 us; speedup vs baseline: 1.1519x; 1.1519x over previous
//
#include <hip/hip_runtime.h>

#define NN 50000
#define NP 50176        // padded per-copy stride (multiple of 256)
#define TT 518
#define KC 32
#define LL 163
#define HH 128
#define EE 1600000
#define NB 196          // node blocks: 196*256 = 50176 >= NN
#define NCOPY 8

// deg copies: deg8[(tid&7)*NP + col] += ea
__global__ __launch_bounds__(256) void k_deg(const int* __restrict__ col,
                                             const float* __restrict__ ea,
                                             float* __restrict__ deg8) {
  int e = blockIdx.x * 256 + threadIdx.x;
  if (e < EE) atomicAdd(&deg8[(threadIdx.x & 7) * NP + col[e]], ea[e]);
}

// dinv = rsqrt(1 + sum of 8 deg copies)
__global__ __launch_bounds__(256) void k_dinv(const float* __restrict__ deg8,
                                              float* __restrict__ dinv) {
  int i = blockIdx.x * 256 + threadIdx.x;
  if (i < NN) {
    float s = 1.0f;
#pragma unroll
    for (int j = 0; j < NCOPY; ++j) s += deg8[j * NP + i];
    dinv[i] = rsqrtf(s);
  }
}

// coef copies: coef8[copy][row] += dinv[row]*ea*dinv[col]
__global__ __launch_bounds__(256) void k_coef(const int* __restrict__ row,
                                              const int* __restrict__ col,
                                              const float* __restrict__ ea,
                                              const float* __restrict__ dinv,
                                              float* __restrict__ coef8) {
  int e = blockIdx.x * 256 + threadIdx.x;
  if (e < EE) {
    int r = row[e];
    atomicAdd(&coef8[(threadIdx.x & 7) * NP + r],
              dinv[r] * ea[e] * dinv[col[e]]);
  }
}

// c[i] = dinv[i]^2 + sum of 8 coef copies
__global__ __launch_bounds__(256) void k_csum(const float* __restrict__ coef8,
                                              const float* __restrict__ dinv,
                                              float* __restrict__ c) {
  int i = blockIdx.x * 256 + threadIdx.x;
  if (i < NN) {
    float di = dinv[i];
    float s = di * di;
#pragma unroll
    for (int j = 0; j < NCOPY; ++j) s += coef8[j * NP + i];
    c[i] = s;
  }
}

// v[l] += sum_n c[n] * relu(conv1d(x[:,n], w[n]) + b[n])[l]
// One thread per node column; 32-slot register ring, slot(t) = t & 31
// (valid: base_t = 96*lc is 0 mod 32). __launch_bounds__(256,4) caps the
// allocator at 128 VGPRs so w[32] + ring[32] stay RESIDENT (R0/R1 lesson:
// default budget made the compiler reload w from global every iteration /
// spill the ring to scratch).
__global__ __launch_bounds__(256, 4) void k_conv(const float* __restrict__ x,
                                                 const float* __restrict__ cw,
                                                 const float* __restrict__ cb,
                                                 const float* __restrict__ c,
                                                 float* __restrict__ v) {
  __shared__ float vloc[32];
  int tid = threadIdx.x;
  if (tid < 32) vloc[tid] = 0.f;
  __syncthreads();

  int nb = blockIdx.x % NB;        // nb fastest: neighbors share lc (I$/L2)
  int lc = blockIdx.x / NB;        // 0..5
  int n = nb * 256 + tid;
  int nc = n < NN ? n : NN - 1;    // clamp for safe loads; cn=0 kills contrib
  float cn = n < NN ? c[n] : 0.f;
  float bn = cb[nc];

  // weights via float4 (16B aligned: nc*KC*4 = nc*128 bytes)
  float w[KC];
  const float4* w4 = (const float4*)(cw + (size_t)nc * KC);
#pragma unroll
  for (int k = 0; k < KC / 4; ++k) {
    float4 t = w4[k];
    w[4 * k] = t.x; w[4 * k + 1] = t.y; w[4 * k + 2] = t.z; w[4 * k + 3] = t.w;
  }

  const float* xp = x + nc;
  int base_t = 96 * lc;
  float xwin[32];
#pragma unroll
  for (int k = 0; k < 32; ++k)     // t = base_t..base_t+31 < 518, no clamp
    xwin[k] = xp[(size_t)(base_t + k) * NN];

  int l0 = 32 * lc;
  int lane = tid & 63;

#pragma unroll
  for (int u = 0; u < 32; ++u) {
    if (l0 + u >= LL) break;       // uniform per block (lc==5 tail: 3 iters)
    float h0 = 0.f, h1 = 0.f, h2 = 0.f, h3 = 0.f;
#pragma unroll
    for (int k = 0; k < KC; k += 4) {
      h0 += xwin[(3 * u + k    ) & 31] * w[k];
      h1 += xwin[(3 * u + k + 1) & 31] * w[k + 1];
      h2 += xwin[(3 * u + k + 2) & 31] * w[k + 2];
      h3 += xwin[(3 * u + k + 3) & 31] * w[k + 3];
    }
    float hv = (h0 + h1) + (h2 + h3) + bn;
    hv = hv > 0.f ? hv : 0.f;
    float val = cn * hv;
#pragma unroll
    for (int off = 1; off < 64; off <<= 1) val += __shfl_xor(val, off, 64);
    if (lane == 0) atomicAdd(&vloc[u], val);
    // slide: t = base_t + 3u + 32..34 into the 3 slots consumed this iter
#pragma unroll
    for (int j = 0; j < 3; ++j) {
      int t = base_t + 3 * u + 32 + j;
      int tc = t < TT ? t : TT - 1;  // clamped values are never read validly
      xwin[(3 * u + j) & 31] = xp[(size_t)tc * NN];
    }
  }

  __syncthreads();
  if (tid < 32 && l0 + tid < LL) atomicAdd(&v[l0 + tid], vloc[tid]);
}

// out[h] = (sum_l v[l]*W[l][h]) / N + gcn_b[h]
__global__ __launch_bounds__(128) void k_out(const float* __restrict__ v,
                                             const float* __restrict__ W,
                                             const float* __restrict__ b,
                                             float* __restrict__ out) {
  int h = threadIdx.x;
  float s = 0.f;
  for (int l = 0; l < LL; ++l) s += v[l] * W[l * HH + h];
  out[h] = s * (1.0f / NN) + b[h];
}

extern "C" void kernel_launch(void* const* d_in, const int* in_sizes, int n_in,
                              void* d_out, int out_size, void* d_ws, size_t ws_size,
                              hipStream_t stream) {
  const float* x  = (const float*)d_in[0];
  const int*   ei = (const int*)d_in[1];
  const float* ea = (const float*)d_in[2];
  const float* cw = (const float*)d_in[3];
  const float* cb = (const float*)d_in[4];
  const float* gW = (const float*)d_in[5];
  const float* gb = (const float*)d_in[6];
  float* out = (float*)d_out;

  float* ws    = (float*)d_ws;
  float* deg8  = ws;                         // NCOPY*NP floats
  float* coef8 = ws + NCOPY * NP;            // NCOPY*NP floats
  float* v     = ws + 2 * NCOPY * NP;        // 256 floats (163 used)
  float* dinv  = ws + 2 * NCOPY * NP + 256;  // NP floats
  float* c     = ws + 2 * NCOPY * NP + 256 + NP;

  const int* row = ei;
  const int* col = ei + EE;

  // zero deg8 + coef8 + v in one contiguous memset
  hipMemsetAsync(deg8, 0, (2 * NCOPY * NP + 256) * sizeof(float), stream);

  k_deg <<<(EE + 255) / 256, 256, 0, stream>>>(col, ea, deg8);
  k_dinv<<<(NN + 255) / 256, 256, 0, stream>>>(deg8, dinv);
  k_coef<<<(EE + 255) / 256, 256, 0, stream>>>(row, col, ea, dinv, coef8);
  k_csum<<<(NN + 255) / 256, 256, 0, stream>>>(coef8, dinv, c);
  k_conv<<<NB * 6, 256, 0, stream>>>(x, cw, cb, c, v);
  k_out <<<1, 128, 0, stream>>>(v, gW, gb, out);
}

// Round 4
// 376.855 us; speedup vs baseline: 1.2474x; 1.0829x over previous
//
#include <hip/hip_runtime.h>

#define NN 50000
#define NP 50176        // padded per-copy stride (multiple of 256)
#define TT 518
#define KC 32
#define LL 163
#define HH 128
#define EE 1600000
#define NB 196          // node blocks: 196*256 = 50176 >= NN
#define NCOPY 8
#define UL 8            // l-values per thread in k_conv
#define XS (3*UL+29)    // 53 x-values per thread
#define NLC ((LL+UL-1)/UL)  // 21 l-chunks

// deg copies, copy = blockIdx&7: consecutive blocks round-robin across the 8
// XCDs, so each copy's cachelines stay in ONE XCD's L2 (R1 lesson: splitting
// by threadIdx&7 left every copy cross-XCD ping-ponging). 4 edges/thread.
__global__ __launch_bounds__(256) void k_deg(const int* __restrict__ col,
                                             const float* __restrict__ ea,
                                             float* __restrict__ deg8) {
  int i = blockIdx.x * 256 + threadIdx.x;
  float* d = deg8 + (blockIdx.x & 7) * NP;
  if (i < EE / 4) {
    int4   c4 = ((const int4*)col)[i];
    float4 a4 = ((const float4*)ea)[i];
    atomicAdd(&d[c4.x], a4.x);
    atomicAdd(&d[c4.y], a4.y);
    atomicAdd(&d[c4.z], a4.z);
    atomicAdd(&d[c4.w], a4.w);
  }
}

// dinv = rsqrt(1 + sum of copies)
__global__ __launch_bounds__(256) void k_dinv(const float* __restrict__ deg8,
                                              float* __restrict__ dinv) {
  int i = blockIdx.x * 256 + threadIdx.x;
  if (i < NN) {
    float s = 1.0f;
#pragma unroll
    for (int j = 0; j < NCOPY; ++j) s += deg8[j * NP + i];
    dinv[i] = rsqrtf(s);
  }
}

// coef copies: coef8[copy][row] += dinv[row]*ea*dinv[col], copy = blockIdx&7
__global__ __launch_bounds__(256) void k_coef(const int* __restrict__ row,
                                              const int* __restrict__ col,
                                              const float* __restrict__ ea,
                                              const float* __restrict__ dinv,
                                              float* __restrict__ coef8) {
  int i = blockIdx.x * 256 + threadIdx.x;
  float* cf = coef8 + (blockIdx.x & 7) * NP;
  if (i < EE / 4) {
    int4   r4 = ((const int4*)row)[i];
    int4   c4 = ((const int4*)col)[i];
    float4 a4 = ((const float4*)ea)[i];
    atomicAdd(&cf[r4.x], dinv[r4.x] * a4.x * dinv[c4.x]);
    atomicAdd(&cf[r4.y], dinv[r4.y] * a4.y * dinv[c4.y]);
    atomicAdd(&cf[r4.z], dinv[r4.z] * a4.z * dinv[c4.z]);
    atomicAdd(&cf[r4.w], dinv[r4.w] * a4.w * dinv[c4.w]);
  }
}

// c[i] = dinv[i]^2 + sum of copies
__global__ __launch_bounds__(256) void k_csum(const float* __restrict__ coef8,
                                              const float* __restrict__ dinv,
                                              float* __restrict__ c) {
  int i = blockIdx.x * 256 + threadIdx.x;
  if (i < NN) {
    float di = dinv[i];
    float s = di * di;
#pragma unroll
    for (int j = 0; j < NCOPY; ++j) s += coef8[j * NP + i];
    c[i] = s;
  }
}

// v[l] += sum_n c[n]*relu(conv(x,w)+b)[l].  Batch mapping: thread = (node,
// 8 consecutive l's). All 53 x-loads + 8 w-loads are INDEPENDENT and pinned
// before the compute via sched_barrier(0) — R0/R2 showed the scheduler
// otherwise sinks each load to just before first use (44 VGPR, 1-iter dep
// distance, 17% VALUBusy latency-bound).
__global__ __launch_bounds__(256, 4) void k_conv(const float* __restrict__ x,
                                                 const float* __restrict__ cw,
                                                 const float* __restrict__ cb,
                                                 const float* __restrict__ c,
                                                 float* __restrict__ v) {
  __shared__ float vloc[UL];
  int tid = threadIdx.x;
  if (tid < UL) vloc[tid] = 0.f;
  __syncthreads();

  int nb = blockIdx.x % NB;
  int lc = blockIdx.x / NB;        // 0..20
  int n = nb * 256 + tid;
  int nc = n < NN ? n : NN - 1;    // clamp for safe loads; cn=0 kills contrib
  float cn = n < NN ? c[n] : 0.f;
  float bn = cb[nc];

  int l0 = lc * UL;
  int t0 = 3 * l0;                 // uniform per block

  // ---- load phase: all independent ----
  float w[KC];
  const float4* w4 = (const float4*)(cw + (size_t)nc * KC);
#pragma unroll
  for (int k = 0; k < KC / 4; ++k) {
    float4 t = w4[k];
    w[4 * k] = t.x; w[4 * k + 1] = t.y; w[4 * k + 2] = t.z; w[4 * k + 3] = t.w;
  }
  const float* xp = x + nc;
  float xs[XS];
#pragma unroll
  for (int j = 0; j < XS; ++j) {
    int t = t0 + j;
    int tc = t < TT ? t : TT - 1;  // only lc==20 clamps; uniform
    xs[j] = xp[(size_t)tc * NN];
  }
  __builtin_amdgcn_sched_barrier(0);   // loads stay ABOVE, compute BELOW

  // ---- compute phase: 8 dots of 32 ----
  float acc[UL];
#pragma unroll
  for (int u = 0; u < UL; ++u) {
    float h0 = 0.f, h1 = 0.f, h2 = 0.f, h3 = 0.f;
#pragma unroll
    for (int k = 0; k < KC; k += 4) {
      h0 += xs[3 * u + k    ] * w[k];
      h1 += xs[3 * u + k + 1] * w[k + 1];
      h2 += xs[3 * u + k + 2] * w[k + 2];
      h3 += xs[3 * u + k + 3] * w[k + 3];
    }
    float hv = (h0 + h1) + (h2 + h3) + bn;
    hv = hv > 0.f ? hv : 0.f;
    acc[u] = cn * hv;
  }

  // ---- reduce: wave-reduce each l, then per-block LDS, then global ----
  int lane = tid & 63;
#pragma unroll
  for (int u = 0; u < UL; ++u) {
    float val = acc[u];
#pragma unroll
    for (int off = 1; off < 64; off <<= 1) val += __shfl_xor(val, off, 64);
    if (lane == 0 && l0 + u < LL) atomicAdd(&vloc[u], val);
  }
  __syncthreads();
  if (tid < UL && l0 + tid < LL) atomicAdd(&v[l0 + tid], vloc[tid]);
}

// out[h] = (sum_l v[l]*W[l][h]) / N + gcn_b[h]
__global__ __launch_bounds__(128) void k_out(const float* __restrict__ v,
                                             const float* __restrict__ W,
                                             const float* __restrict__ b,
                                             float* __restrict__ out) {
  int h = threadIdx.x;
  float s = 0.f;
  for (int l = 0; l < LL; ++l) s += v[l] * W[l * HH + h];
  out[h] = s * (1.0f / NN) + b[h];
}

extern "C" void kernel_launch(void* const* d_in, const int* in_sizes, int n_in,
                              void* d_out, int out_size, void* d_ws, size_t ws_size,
                              hipStream_t stream) {
  const float* x  = (const float*)d_in[0];
  const int*   ei = (const int*)d_in[1];
  const float* ea = (const float*)d_in[2];
  const float* cw = (const float*)d_in[3];
  const float* cb = (const float*)d_in[4];
  const float* gW = (const float*)d_in[5];
  const float* gb = (const float*)d_in[6];
  float* out = (float*)d_out;

  float* ws    = (float*)d_ws;
  float* deg8  = ws;                         // NCOPY*NP floats
  float* coef8 = ws + NCOPY * NP;            // NCOPY*NP floats
  float* v     = ws + 2 * NCOPY * NP;        // 256 floats (163 used)
  float* dinv  = ws + 2 * NCOPY * NP + 256;  // NP floats
  float* c     = ws + 2 * NCOPY * NP + 256 + NP;

  const int* row = ei;
  const int* col = ei + EE;

  // zero deg8 + coef8 + v in one contiguous memset
  hipMemsetAsync(deg8, 0, (2 * NCOPY * NP + 256) * sizeof(float), stream);

  int egrid = (EE / 4 + 255) / 256;   // 1563
  k_deg <<<egrid, 256, 0, stream>>>(col, ea, deg8);
  k_dinv<<<(NN + 255) / 256, 256, 0, stream>>>(deg8, dinv);
  k_coef<<<egrid, 256, 0, stream>>>(row, col, ea, dinv, coef8);
  k_csum<<<(NN + 255) / 256, 256, 0, stream>>>(coef8, dinv, c);
  k_conv<<<NB * NLC, 256, 0, stream>>>(x, cw, cb, c, v);
  k_out <<<1, 128, 0, stream>>>(v, gW, gb, out);
}

// Round 5
// 268.462 us; speedup vs baseline: 1.7511x; 1.4038x over previous
//
#include <hip/hip_runtime.h>

#define NN 50000
#define NP 50176        // padded node stride (multiple of 256)
#define TT 518
#define KC 32
#define LL 163
#define HH 128
#define EE 1600000
#define NB 196          // node blocks: 196*256 = 50176 >= NN
#define NCOPY 8
#define UL 8            // l-values per thread in k_conv
#define XS (3*UL+29)    // 53 x-values per thread
#define NLC ((LL+UL-1)/UL)  // 21 l-chunks

// ---- chunked-LDS scatter (no global atomics) ----
#define CKN 4           // node chunks
#define CSZ 12544       // nodes/chunk (4*12544 = 50176), LDS acc = 50176 B
#define PSL 128         // edge slices (partials per chunk)
#define GSC (CKN*PSL)   // 512 blocks
#define ESL (EE/PSL)    // 12500 edges per slice (divisible by 4)

// deg partials: block (chunk=b&3, p=b>>2) scans slice p, bins col hits into
// LDS, flushes private partial with plain stores. R4 evidence: 1.6M global
// atomics cost 32B fabric transactions each (WRITE_SIZE 49.8MB) — LDS
// privatization removes them entirely.
__global__ __launch_bounds__(256) void k_deg_part(const int* __restrict__ col,
                                                  const float* __restrict__ ea,
                                                  float* __restrict__ part) {
  __shared__ float acc[CSZ];
  int tid = threadIdx.x;
  for (int j = tid; j < CSZ; j += 256) acc[j] = 0.f;
  __syncthreads();
  int chunk = blockIdx.x & (CKN - 1);
  int base = chunk * CSZ;
  const int4*   c4p = (const int4*)col + (blockIdx.x >> 2) * (ESL / 4);
  const float4* a4p = (const float4*)ea + (blockIdx.x >> 2) * (ESL / 4);
  for (int i = tid; i < ESL / 4; i += 256) {
    int4   c4 = c4p[i];
    float4 a4 = a4p[i];
    unsigned jx = (unsigned)(c4.x - base);
    unsigned jy = (unsigned)(c4.y - base);
    unsigned jz = (unsigned)(c4.z - base);
    unsigned jw = (unsigned)(c4.w - base);
    if (jx < CSZ) atomicAdd(&acc[jx], a4.x);
    if (jy < CSZ) atomicAdd(&acc[jy], a4.y);
    if (jz < CSZ) atomicAdd(&acc[jz], a4.z);
    if (jw < CSZ) atomicAdd(&acc[jw], a4.w);
  }
  __syncthreads();
  float* out = part + (size_t)blockIdx.x * CSZ;
  for (int j = tid; j < CSZ; j += 256) out[j] = acc[j];
}

// dinv[i] = rsqrt(1 + sum_p degpart[p][i])
__global__ __launch_bounds__(256) void k_dinv2(const float* __restrict__ part,
                                               float* __restrict__ dinv) {
  int i = blockIdx.x * 256 + threadIdx.x;
  if (i >= NN) return;
  int chunk = i / CSZ, j = i - chunk * CSZ;
  const float* q = part + (size_t)chunk * CSZ + j;
  float s = 1.0f;
#pragma unroll 8
  for (int p = 0; p < PSL; ++p) s += q[(size_t)p * (CKN * CSZ)];
  dinv[i] = rsqrtf(s);
}

// coef partials: acc[row] += ea * dinv[col].  The dinv[row] factor is
// constant per slot -> folded into k_csum2, eliminating 1.6M row-gathers.
__global__ __launch_bounds__(256) void k_coef_part(const int* __restrict__ row,
                                                   const int* __restrict__ col,
                                                   const float* __restrict__ ea,
                                                   const float* __restrict__ dinv,
                                                   float* __restrict__ part) {
  __shared__ float acc[CSZ];
  int tid = threadIdx.x;
  for (int j = tid; j < CSZ; j += 256) acc[j] = 0.f;
  __syncthreads();
  int chunk = blockIdx.x & (CKN - 1);
  int base = chunk * CSZ;
  const int4*   r4p = (const int4*)row + (blockIdx.x >> 2) * (ESL / 4);
  const int4*   c4p = (const int4*)col + (blockIdx.x >> 2) * (ESL / 4);
  const float4* a4p = (const float4*)ea + (blockIdx.x >> 2) * (ESL / 4);
  for (int i = tid; i < ESL / 4; i += 256) {
    int4   r4 = r4p[i];
    int4   c4 = c4p[i];
    float4 a4 = a4p[i];
    unsigned jx = (unsigned)(r4.x - base);
    unsigned jy = (unsigned)(r4.y - base);
    unsigned jz = (unsigned)(r4.z - base);
    unsigned jw = (unsigned)(r4.w - base);
    if (jx < CSZ) atomicAdd(&acc[jx], a4.x * dinv[c4.x]);
    if (jy < CSZ) atomicAdd(&acc[jy], a4.y * dinv[c4.y]);
    if (jz < CSZ) atomicAdd(&acc[jz], a4.z * dinv[c4.z]);
    if (jw < CSZ) atomicAdd(&acc[jw], a4.w * dinv[c4.w]);
  }
  __syncthreads();
  float* out = part + (size_t)blockIdx.x * CSZ;
  for (int j = tid; j < CSZ; j += 256) out[j] = acc[j];
}

// c[i] = dinv[i]^2 + dinv[i] * sum_p coefpart[p][i]
__global__ __launch_bounds__(256) void k_csum2(const float* __restrict__ part,
                                               const float* __restrict__ dinv,
                                               float* __restrict__ c) {
  int i = blockIdx.x * 256 + threadIdx.x;
  if (i >= NN) return;
  int chunk = i / CSZ, j = i - chunk * CSZ;
  const float* q = part + (size_t)chunk * CSZ + j;
  float s = 0.0f;
#pragma unroll 8
  for (int p = 0; p < PSL; ++p) s += q[(size_t)p * (CKN * CSZ)];
  float di = dinv[i];
  c[i] = di * di + di * s;
}

// ---- fallback path (R4 global-atomic version) if ws is too small ----
__global__ __launch_bounds__(256) void k_deg(const int* __restrict__ col,
                                             const float* __restrict__ ea,
                                             float* __restrict__ deg8) {
  int i = blockIdx.x * 256 + threadIdx.x;
  float* d = deg8 + (blockIdx.x & 7) * NP;
  if (i < EE / 4) {
    int4   c4 = ((const int4*)col)[i];
    float4 a4 = ((const float4*)ea)[i];
    atomicAdd(&d[c4.x], a4.x);
    atomicAdd(&d[c4.y], a4.y);
    atomicAdd(&d[c4.z], a4.z);
    atomicAdd(&d[c4.w], a4.w);
  }
}
__global__ __launch_bounds__(256) void k_dinv(const float* __restrict__ deg8,
                                              float* __restrict__ dinv) {
  int i = blockIdx.x * 256 + threadIdx.x;
  if (i < NN) {
    float s = 1.0f;
#pragma unroll
    for (int j = 0; j < NCOPY; ++j) s += deg8[j * NP + i];
    dinv[i] = rsqrtf(s);
  }
}
__global__ __launch_bounds__(256) void k_coef(const int* __restrict__ row,
                                              const int* __restrict__ col,
                                              const float* __restrict__ ea,
                                              const float* __restrict__ dinv,
                                              float* __restrict__ coef8) {
  int i = blockIdx.x * 256 + threadIdx.x;
  float* cf = coef8 + (blockIdx.x & 7) * NP;
  if (i < EE / 4) {
    int4   r4 = ((const int4*)row)[i];
    int4   c4 = ((const int4*)col)[i];
    float4 a4 = ((const float4*)ea)[i];
    atomicAdd(&cf[r4.x], a4.x * dinv[c4.x] * dinv[r4.x]);
    atomicAdd(&cf[r4.y], a4.y * dinv[c4.y] * dinv[r4.y]);
    atomicAdd(&cf[r4.z], a4.z * dinv[c4.z] * dinv[r4.z]);
    atomicAdd(&cf[r4.w], a4.w * dinv[c4.w] * dinv[r4.w]);
  }
}
__global__ __launch_bounds__(256) void k_csum(const float* __restrict__ coef8,
                                              const float* __restrict__ dinv,
                                              float* __restrict__ c) {
  int i = blockIdx.x * 256 + threadIdx.x;
  if (i < NN) {
    float di = dinv[i];
    float s = di * di;
#pragma unroll
    for (int j = 0; j < NCOPY; ++j) s += coef8[j * NP + i];
    c[i] = s;
  }
}

// v[l] += sum_n c[n]*relu(conv(x,w)+b)[l].  Batch mapping: thread = (node,
// 8 consecutive l's); all 53 x-loads + 8 w-loads independent, pinned above
// compute via sched_barrier(0).
__global__ __launch_bounds__(256, 4) void k_conv(const float* __restrict__ x,
                                                 const float* __restrict__ cw,
                                                 const float* __restrict__ cb,
                                                 const float* __restrict__ c,
                                                 float* __restrict__ v) {
  __shared__ float vloc[UL];
  int tid = threadIdx.x;
  if (tid < UL) vloc[tid] = 0.f;
  __syncthreads();

  int nb = blockIdx.x % NB;
  int lc = blockIdx.x / NB;        // 0..20
  int n = nb * 256 + tid;
  int nc = n < NN ? n : NN - 1;    // clamp for safe loads; cn=0 kills contrib
  float cn = n < NN ? c[n] : 0.f;
  float bn = cb[nc];

  int l0 = lc * UL;
  int t0 = 3 * l0;

  float w[KC];
  const float4* w4 = (const float4*)(cw + (size_t)nc * KC);
#pragma unroll
  for (int k = 0; k < KC / 4; ++k) {
    float4 t = w4[k];
    w[4 * k] = t.x; w[4 * k + 1] = t.y; w[4 * k + 2] = t.z; w[4 * k + 3] = t.w;
  }
  const float* xp = x + nc;
  float xs[XS];
#pragma unroll
  for (int j = 0; j < XS; ++j) {
    int t = t0 + j;
    int tc = t < TT ? t : TT - 1;  // only lc==20 clamps; uniform
    xs[j] = xp[(size_t)tc * NN];
  }
  __builtin_amdgcn_sched_barrier(0);   // loads stay ABOVE, compute BELOW

  float acc[UL];
#pragma unroll
  for (int u = 0; u < UL; ++u) {
    float h0 = 0.f, h1 = 0.f, h2 = 0.f, h3 = 0.f;
#pragma unroll
    for (int k = 0; k < KC; k += 4) {
      h0 += xs[3 * u + k    ] * w[k];
      h1 += xs[3 * u + k + 1] * w[k + 1];
      h2 += xs[3 * u + k + 2] * w[k + 2];
      h3 += xs[3 * u + k + 3] * w[k + 3];
    }
    float hv = (h0 + h1) + (h2 + h3) + bn;
    hv = hv > 0.f ? hv : 0.f;
    acc[u] = cn * hv;
  }

  int lane = tid & 63;
#pragma unroll
  for (int u = 0; u < UL; ++u) {
    float val = acc[u];
#pragma unroll
    for (int off = 1; off < 64; off <<= 1) val += __shfl_xor(val, off, 64);
    if (lane == 0 && l0 + u < LL) atomicAdd(&vloc[u], val);
  }
  __syncthreads();
  if (tid < UL && l0 + tid < LL) atomicAdd(&v[l0 + tid], vloc[tid]);
}

// out[h] = (sum_l v[l]*W[l][h]) / N + gcn_b[h]
__global__ __launch_bounds__(128) void k_out(const float* __restrict__ v,
                                             const float* __restrict__ W,
                                             const float* __restrict__ b,
                                             float* __restrict__ out) {
  int h = threadIdx.x;
  float s = 0.f;
  for (int l = 0; l < LL; ++l) s += v[l] * W[l * HH + h];
  out[h] = s * (1.0f / NN) + b[h];
}

extern "C" void kernel_launch(void* const* d_in, const int* in_sizes, int n_in,
                              void* d_out, int out_size, void* d_ws, size_t ws_size,
                              hipStream_t stream) {
  const float* x  = (const float*)d_in[0];
  const int*   ei = (const int*)d_in[1];
  const float* ea = (const float*)d_in[2];
  const float* cw = (const float*)d_in[3];
  const float* cb = (const float*)d_in[4];
  const float* gW = (const float*)d_in[5];
  const float* gb = (const float*)d_in[6];
  float* out = (float*)d_out;

  const int* row = ei;
  const int* col = ei + EE;
  float* ws = (float*)d_ws;

  size_t need_new = ((size_t)GSC * CSZ + 256 + 2 * NP) * sizeof(float);
  if (ws_size >= need_new) {
    float* part = ws;                          // GSC*CSZ floats (reused deg->coef)
    float* v    = ws + (size_t)GSC * CSZ;      // 256 floats
    float* dinv = v + 256;                     // NP floats
    float* c    = dinv + NP;                   // NP floats
    hipMemsetAsync(v, 0, 256 * sizeof(float), stream);
    k_deg_part <<<GSC, 256, 0, stream>>>(col, ea, part);
    k_dinv2    <<<NB, 256, 0, stream>>>(part, dinv);
    k_coef_part<<<GSC, 256, 0, stream>>>(row, col, ea, dinv, part);
    k_csum2    <<<NB, 256, 0, stream>>>(part, dinv, c);
    k_conv     <<<NB * NLC, 256, 0, stream>>>(x, cw, cb, c, v);
    k_out      <<<1, 128, 0, stream>>>(v, gW, gb, out);
  } else {
    float* deg8  = ws;
    float* coef8 = ws + NCOPY * NP;
    float* v     = ws + 2 * NCOPY * NP;
    float* dinv  = ws + 2 * NCOPY * NP + 256;
    float* c     = ws + 2 * NCOPY * NP + 256 + NP;
    hipMemsetAsync(deg8, 0, (2 * NCOPY * NP + 256) * sizeof(float), stream);
    int egrid = (EE / 4 + 255) / 256;
    k_deg <<<egrid, 256, 0, stream>>>(col, ea, deg8);
    k_dinv<<<NB, 256, 0, stream>>>(deg8, dinv);
    k_coef<<<egrid, 256, 0, stream>>>(row, col, ea, dinv, coef8);
    k_csum<<<NB, 256, 0, stream>>>(coef8, dinv, c);
    k_conv<<<NB * NLC, 256, 0, stream>>>(x, cw, cb, c, v);
    k_out <<<1, 128, 0, stream>>>(v, gW, gb, out);
  }
}